// Round 3
// baseline (2400.711 us; speedup 1.0000x reference)
//
#include <hip/hip_runtime.h>

typedef short bf16x8 __attribute__((ext_vector_type(8)));
typedef float f32x4 __attribute__((ext_vector_type(4)));
typedef float f32x16 __attribute__((ext_vector_type(16)));

#define AS 264            // plain layout; 528B row stride => <=2-way LDS aliasing (free)
#define T0OFF (32 * AS)
#define T1OFF (64 * AS)

__device__ __forceinline__ unsigned short f2bf(float f) {      // RNE (pre-kernels only)
    union { float f; unsigned int u; } v; v.f = f;
    unsigned int u = v.u + 0x7FFFu + ((v.u >> 16) & 1u);
    return (unsigned short)(u >> 16);
}
// HW packed f32x2 -> bf16x2 (RNE), 1 VALU op. dst.lo = a, dst.hi = b.
__device__ __forceinline__ unsigned cvtpk(float a, float b) {
    unsigned r;
    asm("v_cvt_pk_bf16_f32 %0, %1, %2" : "=v"(r) : "v"(a), "v"(b));
    return r;
}
__device__ __forceinline__ float bf2f(unsigned int h) {
    union { unsigned int u; float f; } v; v.u = h << 16; return v.f;
}
__device__ __forceinline__ float sigm(float x) {
    return __builtin_amdgcn_rcpf(1.0f + __expf(-x));
}

struct f4s { float v[4]; };
__device__ __forceinline__ f4s ld4(const float* p) {
    float4 t = *(const float4*)p;
    f4s r; r.v[0] = t.x; r.v[1] = t.y; r.v[2] = t.z; r.v[3] = t.w; return r;
}

// ---------------- pre-kernels ----------------

__global__ void k_base(const float* __restrict__ ctx,
                       const float* __restrict__ w1,
                       const float* __restrict__ b1,
                       float* __restrict__ base) {
    const int b = blockIdx.x, n = threadIdx.x;
    float acc = b1[n];
    for (int c = 0; c < 128; ++c)
        acc += ctx[b * 128 + c] * w1[(3 + c) * 256 + n];
    base[b * 256 + n] = acc;
}

// 32x32x16 A-operand fragments: unit (kk,hb,lane) holds 8 bf16:
// wf[((kk*8+hb)*64+lane)*8 + j] = bf16( W[kk*16 + (lane>>5)*8 + j][hb*32 + (lane&31)] )
__global__ void k_frag(const float* __restrict__ w,
                       unsigned short* __restrict__ wf) {
    const int t = blockIdx.x * blockDim.x + threadIdx.x;  // 0..65535
    const int j = t & 7, lane = (t >> 3) & 63, hb = (t >> 9) & 7, kk = t >> 12;
    const int c = kk * 16 + (lane >> 5) * 8 + j;
    const int h = hb * 32 + (lane & 31);
    wf[t] = f2bf(w[c * 256 + h]);
}

// ---------------- gemm: 32x32x16, wave owns hidden block hb (32) x all 32 points ----------
// D[row=hidden hb*32 + (reg&3)+8*(reg>>2)+4*kh][col=point lane&31]
__device__ __forceinline__ void do_gemm32(const unsigned short* __restrict__ wf,
                                          const unsigned short* Asl,
                                          int abase, int wub,
                                          f32x16& aP, f32x16& aT0, f32x16& aT1) {
    const bf16x8* __restrict__ wp = (const bf16x8*)wf;
    bf16x8 buf[4];
#pragma unroll
    for (int i = 0; i < 4; ++i) buf[i] = wp[wub + i * 512];
#pragma unroll 1
    for (int kk = 0; kk < 12; kk += 4) {
#pragma unroll
        for (int u = 0; u < 4; ++u) {
            const int koff = (kk + u) * 16;
            const bf16x8 fP  = *(const bf16x8*)(Asl + abase + koff);
            const bf16x8 fT0 = *(const bf16x8*)(Asl + abase + koff + T0OFF);
            const bf16x8 fT1 = *(const bf16x8*)(Asl + abase + koff + T1OFF);
            aP  = __builtin_amdgcn_mfma_f32_32x32x16_bf16(buf[u], fP,  aP,  0, 0, 0);
            aT0 = __builtin_amdgcn_mfma_f32_32x32x16_bf16(buf[u], fT0, aT0, 0, 0, 0);
            aT1 = __builtin_amdgcn_mfma_f32_32x32x16_bf16(buf[u], fT1, aT1, 0, 0, 0);
            buf[u] = wp[wub + (kk + 4 + u) * 512];          // prefetch distance 4
        }
    }
#pragma unroll
    for (int u = 0; u < 4; ++u) {                           // kk = 12..15, no prefetch
        const int koff = (12 + u) * 16;
        const bf16x8 fP  = *(const bf16x8*)(Asl + abase + koff);
        const bf16x8 fT0 = *(const bf16x8*)(Asl + abase + koff + T0OFF);
        const bf16x8 fT1 = *(const bf16x8*)(Asl + abase + koff + T1OFF);
        aP  = __builtin_amdgcn_mfma_f32_32x32x16_bf16(buf[u], fP,  aP,  0, 0, 0);
        aT0 = __builtin_amdgcn_mfma_f32_32x32x16_bf16(buf[u], fT0, aT0, 0, 0, 0);
        aT1 = __builtin_amdgcn_mfma_f32_32x32x16_bf16(buf[u], fT1, aT1, 0, 0, 0);
    }
}

// epilogue: lane (p=lane&31, kh=lane>>5) holds, per g=0..3, hidden units
// hb*32 + 4*kh + 8*g + {0..3} of point p -> one 8B packed write per array per g.
__device__ __forceinline__ void el_write32(unsigned short* Asl,
                                           const f32x16& aP, const f32x16& aT0, const f32x16& aT1,
                                           int ebase) {   // ebase = p*AS + hb*32 + 4*kh
#pragma unroll
    for (int g = 0; g < 4; ++g) {
        float h[4], t0[4], t1[4];
#pragma unroll
        for (int e = 0; e < 4; ++e) {
            const float pre = aP[4 * g + e];        // bias already in acc
            const float s = sigm(pre);
            const float hv = pre * s;
            const float dd = fmaf(hv, 1.0f - s, s); // silu'(pre)
            h[e]  = hv;
            t0[e] = dd * aT0[4 * g + e];
            t1[e] = dd * aT1[4 * g + e];
        }
        uint2 v0, v1, v2;
        v0.x = cvtpk(h[0],  h[1]);  v0.y = cvtpk(h[2],  h[3]);
        v1.x = cvtpk(t0[0], t0[1]); v1.y = cvtpk(t0[2], t0[3]);
        v2.x = cvtpk(t1[0], t1[1]); v2.y = cvtpk(t1[2], t1[3]);
        *(uint2*)(Asl + ebase + 8 * g)         = v0;
        *(uint2*)(Asl + ebase + 8 * g + T0OFF) = v1;
        *(uint2*)(Asl + ebase + 8 * g + T1OFF) = v2;
    }
}

// ---------------- main kernel ----------------
// One WG = 32 points, 512 threads (8 waves), 2 WGs/CU -> 16 waves/CU.
// Wave w owns hidden block hb=w (32 units) x all 32 points: weight tiles read once
// per WG (dup_B=1, halves L1/TA traffic vs 16x16 tw-split), 32x32x16 MFMA.
__launch_bounds__(512, 4)
__global__ void k_main(const float* __restrict__ x,
                       const float* __restrict__ w1,
                       const float* __restrict__ b2g,
                       const float* __restrict__ b3g,
                       const float* __restrict__ w4g,
                       const float* __restrict__ b4g,
                       const unsigned short* __restrict__ w2f,
                       const unsigned short* __restrict__ w3f,
                       const float* __restrict__ basep,
                       float* __restrict__ ldacc,
                       float* __restrict__ out) {
    __shared__ unsigned short Asl[96 * AS];    // [h;t0;t1] bf16, plain (32 rows each)
    __shared__ float w1r[3][256];
    __shared__ float basel[256];
    __shared__ float w40[256], w41[256];
    __shared__ float b2l[256], b3l[256];
    __shared__ float px[32][2];                // per-point position
    __shared__ float pld[32];                  // per-point logdet accumulator

    const int tid = threadIdx.x;
    const int wg = blockIdx.x;
    const int b = wg >> 7;                // 128 WGs per batch
    const int n0 = (wg & 127) << 5;       // 32 points per WG

    for (int i = tid; i < 768; i += 512) w1r[i >> 8][i & 255] = w1[i];
    if (tid < 256) {
        basel[tid] = basep[b * 256 + tid];
        w40[tid] = w4g[2 * tid]; w41[tid] = w4g[2 * tid + 1];
        b2l[tid] = b2g[tid];     b3l[tid] = b3g[tid];
    }
    if (tid < 64) ((float*)px)[tid] = x[((b << 12) + n0) * 2 + tid];  // coalesced 32x(x0,x1)
    if (tid < 32) pld[tid] = 0.0f;

    const int lane = tid & 63, wave = tid >> 6;
    const int p = lane & 31, kh = lane >> 5;
    const int hb = wave;                                      // hidden block (32 units)
    const int abase = p * AS + kh * 8;                        // act-frag base (+kk*16)
    const int ebase = p * AS + hb * 32 + kh * 4;              // el_write base
    const int wub   = hb * 64 + lane;                         // weight bf16x8-unit base (+kk*512)
    const int bbase = hb * 32 + kh * 4;                       // bias seed base (+8*g)

    const int p4 = tid >> 4;            // point (0..31)
    const int ic = tid & 15;            // 16 threads per point

    const float b40 = b4g[0], b41 = b4g[1];
    __syncthreads();

#pragma unroll 1
    for (int st = 0; st < 10; ++st) {
        const float ti = 0.1f * (float)st;
        // ---------- layer 1 (fused with previous step's L4; registers only) ----------
        // cb = g*64 + ic*4: 16B/lane stride across ic -> conflict-free w1r/basel access
        const float x0 = px[p4][0];   // broadcast ds_read (same wave wrote it)
        const float x1 = px[p4][1];
#pragma unroll
        for (int g = 0; g < 4; ++g) {
            const int cb = g * 64 + (ic << 2);
            const f4s wa = ld4(&w1r[0][cb]);
            const f4s wb = ld4(&w1r[1][cb]);
            const f4s wc = ld4(&w1r[2][cb]);
            const f4s bs = ld4(&basel[cb]);
            float hf[4], t0f[4], t1f[4];
#pragma unroll
            for (int e = 0; e < 4; ++e) {
                const float pre = x0 * wa.v[e] + x1 * wb.v[e] + ti * wc.v[e] + bs.v[e];
                const float s = sigm(pre);
                const float h = pre * s;
                const float d = fmaf(h, 1.0f - s, s);
                hf[e]  = h;
                t0f[e] = d * wa.v[e];
                t1f[e] = d * wb.v[e];
            }
            uint2 v0, v1, v2;
            v0.x = cvtpk(hf[0],  hf[1]);  v0.y = cvtpk(hf[2],  hf[3]);
            v1.x = cvtpk(t0f[0], t0f[1]); v1.y = cvtpk(t0f[2], t0f[3]);
            v2.x = cvtpk(t1f[0], t1f[1]); v2.y = cvtpk(t1f[2], t1f[3]);
            *(uint2*)(Asl + p4 * AS + cb) = v0;
            *(uint2*)(Asl + T0OFF + p4 * AS + cb) = v1;
            *(uint2*)(Asl + T1OFF + p4 * AS + cb) = v2;
        }
        __syncthreads();

        // ---------- layer 2 ----------
        f32x16 aP, aT0, aT1;
#pragma unroll
        for (int g = 0; g < 4; ++g) {
            const float4 bv = *(const float4*)&b2l[bbase + 8 * g];   // broadcast read
            aP[4 * g + 0] = bv.x; aP[4 * g + 1] = bv.y;
            aP[4 * g + 2] = bv.z; aP[4 * g + 3] = bv.w;
        }
#pragma unroll
        for (int r = 0; r < 16; ++r) { aT0[r] = 0.f; aT1[r] = 0.f; }
        do_gemm32(w2f, Asl, abase, wub, aP, aT0, aT1);
        __syncthreads();                      // all waves done READING Asl before overwrite
        el_write32(Asl, aP, aT0, aT1, ebase);
        __syncthreads();

        // ---------- layer 3 ----------
#pragma unroll
        for (int g = 0; g < 4; ++g) {
            const float4 bv = *(const float4*)&b3l[bbase + 8 * g];
            aP[4 * g + 0] = bv.x; aP[4 * g + 1] = bv.y;
            aP[4 * g + 2] = bv.z; aP[4 * g + 3] = bv.w;
        }
#pragma unroll
        for (int r = 0; r < 16; ++r) { aT0[r] = 0.f; aT1[r] = 0.f; }
        do_gemm32(w3f, Asl, abase, wub, aP, aT0, aT1);
        __syncthreads();
        el_write32(Asl, aP, aT0, aT1, ebase);
        __syncthreads();

        // ---------- layer 4 + point update (same-wave LDS state; no trailing barrier) ----------
        {
            float v0 = 0.f, v1 = 0.f, j00 = 0.f, j11 = 0.f;
#pragma unroll
            for (int g = 0; g < 4; ++g) {
                const int cb = g * 64 + (ic << 2);
                const uint2 hv  = *(const uint2*)(Asl + p4 * AS + cb);
                const uint2 t0v = *(const uint2*)(Asl + T0OFF + p4 * AS + cb);
                const uint2 t1v = *(const uint2*)(Asl + T1OFF + p4 * AS + cb);
                const f4s wa = ld4(&w40[cb]);
                const f4s wb = ld4(&w41[cb]);
                const unsigned hu[4]  = { hv.x & 0xffffu,  hv.x >> 16,  hv.y & 0xffffu,  hv.y >> 16 };
                const unsigned t0u[4] = { t0v.x & 0xffffu, t0v.x >> 16, t0v.y & 0xffffu, t0v.y >> 16 };
                const unsigned t1u[4] = { t1v.x & 0xffffu, t1v.x >> 16, t1v.y & 0xffffu, t1v.y >> 16 };
#pragma unroll
                for (int e = 0; e < 4; ++e) {
                    const float h = bf2f(hu[e]);
                    v0  += h * wa.v[e];
                    v1  += h * wb.v[e];
                    j00 += bf2f(t0u[e]) * wa.v[e];
                    j11 += bf2f(t1u[e]) * wb.v[e];
                }
            }
#pragma unroll
            for (int o = 1; o < 16; o <<= 1) {   // butterfly across the point's 16 lanes
                v0  += __shfl_xor(v0, o);
                v1  += __shfl_xor(v1, o);
                j00 += __shfl_xor(j00, o);
                j11 += __shfl_xor(j11, o);
            }
            if (ic == 0) {                       // same wave as the 16 reader lanes
                px[p4][0] += 0.1f * (v0 + b40);
                px[p4][1] += 0.1f * (v1 + b41);
                pld[p4]   += 0.1f * (j00 + j11);
            }
            // next L1 reads px (same wave) and overwrites the Asl addresses this
            // thread just read: no barrier.
        }
    }

    // ---------- epilogue: FP32 output ----------
    if (ic == 0) {
        out[((b << 12) + n0 + p4) * 2]     = px[p4][0];
        out[((b << 12) + n0 + p4) * 2 + 1] = px[p4][1];
    }
    __syncthreads();
    if (wave == 0) {
        float v = (lane < 32) ? pld[lane] : 0.0f;
#pragma unroll
        for (int o = 32; o > 0; o >>= 1) v += __shfl_xor(v, o);
        if (lane == 0) atomicAdd(ldacc + b, v);
    }
}

// copy 64 float accumulators -> fp32 logdet outputs
__global__ void k_fin(const float* __restrict__ ldacc, float* __restrict__ out) {
    out[524288 + threadIdx.x] = ldacc[threadIdx.x];
}

extern "C" void kernel_launch(void* const* d_in, const int* in_sizes, int n_in,
                              void* d_out, int out_size, void* d_ws, size_t ws_size,
                              hipStream_t stream) {
    const float* x   = (const float*)d_in[0];
    const float* ctx = (const float*)d_in[1];
    const float* w1  = (const float*)d_in[2];
    const float* b1  = (const float*)d_in[3];
    const float* w2  = (const float*)d_in[4];
    const float* b2  = (const float*)d_in[5];
    const float* w3  = (const float*)d_in[6];
    const float* b3  = (const float*)d_in[7];
    const float* w4  = (const float*)d_in[8];
    const float* b4  = (const float*)d_in[9];

    // d_ws layout: [0,128K) w2f bf16 | [128K,256K) w3f bf16 | [256K,320K) base fp32 | [320K,+256) ldacc
    char* ws = (char*)d_ws;
    unsigned short* w2f = (unsigned short*)ws;
    unsigned short* w3f = (unsigned short*)(ws + 131072);
    float* basep = (float*)(ws + 262144);
    float* ldacc = (float*)(ws + 327680);
    float* out = (float*)d_out;

    hipMemsetAsync(ldacc, 0, 64 * sizeof(float), stream);
    k_base<<<dim3(64), dim3(256), 0, stream>>>(ctx, w1, b1, basep);
    k_frag<<<dim3(128), dim3(512), 0, stream>>>(w2, w2f);
    k_frag<<<dim3(128), dim3(512), 0, stream>>>(w3, w3f);
    k_main<<<dim3(8192), dim3(512), 0, stream>>>(x, w1, b2, b3, w4, b4, w2f, w3f, basep, ldacc, out);
    k_fin<<<dim3(1), dim3(64), 0, stream>>>(ldacc, out);
}

// Round 4
// 2236.434 us; speedup vs baseline: 1.0735x; 1.0735x over previous
//
#include <hip/hip_runtime.h>

typedef short bf16x8 __attribute__((ext_vector_type(8)));
typedef float f32x4 __attribute__((ext_vector_type(4)));
typedef float f32x16 __attribute__((ext_vector_type(16)));

#define AS 264            // plain layout; 528B row stride => <=2-way LDS aliasing (free)
#define T0OFF (32 * AS)
#define T1OFF (64 * AS)

__device__ __forceinline__ unsigned short f2bf(float f) {      // RNE (pre-kernels only)
    union { float f; unsigned int u; } v; v.f = f;
    unsigned int u = v.u + 0x7FFFu + ((v.u >> 16) & 1u);
    return (unsigned short)(u >> 16);
}
// HW packed f32x2 -> bf16x2 (RNE), 1 VALU op. dst.lo = a, dst.hi = b.
__device__ __forceinline__ unsigned cvtpk(float a, float b) {
    unsigned r;
    asm("v_cvt_pk_bf16_f32 %0, %1, %2" : "=v"(r) : "v"(a), "v"(b));
    return r;
}
__device__ __forceinline__ float bf2f(unsigned int h) {
    union { unsigned int u; float f; } v; v.u = h << 16; return v.f;
}
__device__ __forceinline__ float sigm(float x) {
    return __builtin_amdgcn_rcpf(1.0f + __expf(-x));
}

struct f4s { float v[4]; };
__device__ __forceinline__ f4s ld4(const float* p) {
    float4 t = *(const float4*)p;
    f4s r; r.v[0] = t.x; r.v[1] = t.y; r.v[2] = t.z; r.v[3] = t.w; return r;
}

// ---------------- pre-kernels ----------------

__global__ void k_base(const float* __restrict__ ctx,
                       const float* __restrict__ w1,
                       const float* __restrict__ b1,
                       float* __restrict__ base) {
    const int b = blockIdx.x, n = threadIdx.x;
    float acc = b1[n];
    for (int c = 0; c < 128; ++c)
        acc += ctx[b * 128 + c] * w1[(3 + c) * 256 + n];
    base[b * 256 + n] = acc;
}

// 32x32x16 A-operand fragments: unit (kk,hb,lane) holds 8 bf16:
// wf[((kk*8+hb)*64+lane)*8 + j] = bf16( W[kk*16 + (lane>>5)*8 + j][hb*32 + (lane&31)] )
__global__ void k_frag(const float* __restrict__ w,
                       unsigned short* __restrict__ wf) {
    const int t = blockIdx.x * blockDim.x + threadIdx.x;  // 0..65535
    const int j = t & 7, lane = (t >> 3) & 63, hb = (t >> 9) & 7, kk = t >> 12;
    const int c = kk * 16 + (lane >> 5) * 8 + j;
    const int h = hb * 32 + (lane & 31);
    wf[t] = f2bf(w[c * 256 + h]);
}

// ---------------- gemm: 32x32x16, wave owns TWO hidden blocks (64 units) x 32 points ----
// Each LDS fragment read now feeds 6 MFMAs (was 3): halves per-CU LDS read traffic.
// D[row=hidden hb*32 + (reg&3)+8*(reg>>2)+4*kh][col=point lane&31]
#define MFMA6(koff, w0, w1)                                                        \
    {                                                                              \
        const bf16x8 fP  = *(const bf16x8*)(Asl + abase + (koff));                 \
        const bf16x8 fT0 = *(const bf16x8*)(Asl + abase + (koff) + T0OFF);         \
        const bf16x8 fT1 = *(const bf16x8*)(Asl + abase + (koff) + T1OFF);         \
        aP0  = __builtin_amdgcn_mfma_f32_32x32x16_bf16(w0, fP,  aP0,  0, 0, 0);    \
        aT00 = __builtin_amdgcn_mfma_f32_32x32x16_bf16(w0, fT0, aT00, 0, 0, 0);    \
        aT10 = __builtin_amdgcn_mfma_f32_32x32x16_bf16(w0, fT1, aT10, 0, 0, 0);    \
        aP1  = __builtin_amdgcn_mfma_f32_32x32x16_bf16(w1, fP,  aP1,  0, 0, 0);    \
        aT01 = __builtin_amdgcn_mfma_f32_32x32x16_bf16(w1, fT0, aT01, 0, 0, 0);    \
        aT11 = __builtin_amdgcn_mfma_f32_32x32x16_bf16(w1, fT1, aT11, 0, 0, 0);    \
    }

// epilogue: lane (p=lane&31, kh=lane>>5) holds, per g=0..3, hidden units
// hb*32 + 4*kh + 8*g + {0..3} of point p -> one 8B packed write per array per g.
__device__ __forceinline__ void el_write32(unsigned short* Asl,
                                           const f32x16& aP, const f32x16& aT0, const f32x16& aT1,
                                           int ebase) {   // ebase = p*AS + hb*32 + 4*kh
#pragma unroll
    for (int g = 0; g < 4; ++g) {
        float h[4], t0[4], t1[4];
#pragma unroll
        for (int e = 0; e < 4; ++e) {
            const float pre = aP[4 * g + e];        // bias already in acc
            const float s = sigm(pre);
            const float hv = pre * s;
            const float dd = fmaf(hv, 1.0f - s, s); // silu'(pre)
            h[e]  = hv;
            t0[e] = dd * aT0[4 * g + e];
            t1[e] = dd * aT1[4 * g + e];
        }
        uint2 v0, v1, v2;
        v0.x = cvtpk(h[0],  h[1]);  v0.y = cvtpk(h[2],  h[3]);
        v1.x = cvtpk(t0[0], t0[1]); v1.y = cvtpk(t0[2], t0[3]);
        v2.x = cvtpk(t1[0], t1[1]); v2.y = cvtpk(t1[2], t1[3]);
        *(uint2*)(Asl + ebase + 8 * g)         = v0;
        *(uint2*)(Asl + ebase + 8 * g + T0OFF) = v1;
        *(uint2*)(Asl + ebase + 8 * g + T1OFF) = v2;
    }
}

// ---------------- main kernel ----------------
// One WG = 32 points, 256 threads (4 waves), 2 WGs/CU -> 8 waves/CU.
// Wave w owns hidden blocks {2w, 2w+1} (64 units) x all 32 points: activation LDS
// fragment reads amortized over 6 MFMAs (halved per-CU LDS traffic vs R3).
__launch_bounds__(256, 2)
__global__ void k_main(const float* __restrict__ x,
                       const float* __restrict__ w1,
                       const float* __restrict__ b2g,
                       const float* __restrict__ b3g,
                       const float* __restrict__ w4g,
                       const float* __restrict__ b4g,
                       const unsigned short* __restrict__ w2f,
                       const unsigned short* __restrict__ w3f,
                       const float* __restrict__ basep,
                       float* __restrict__ ldacc,
                       float* __restrict__ out) {
    __shared__ unsigned short Asl[96 * AS];    // [h;t0;t1] bf16, plain (32 rows each)
    __shared__ float w1r[3][256];
    __shared__ float basel[256];
    __shared__ float w40[256], w41[256];
    __shared__ float b2l[256], b3l[256];
    __shared__ float px[32][2];                // per-point position
    __shared__ float pld[32];                  // per-point logdet accumulator

    const int tid = threadIdx.x;
    const int wg = blockIdx.x;
    const int b = wg >> 7;                // 128 WGs per batch
    const int n0 = (wg & 127) << 5;       // 32 points per WG

    for (int i = tid; i < 768; i += 256) w1r[i >> 8][i & 255] = w1[i];
    {
        basel[tid] = basep[b * 256 + tid];
        w40[tid] = w4g[2 * tid]; w41[tid] = w4g[2 * tid + 1];
        b2l[tid] = b2g[tid];     b3l[tid] = b3g[tid];
    }
    if (tid < 64) ((float*)px)[tid] = x[((b << 12) + n0) * 2 + tid];  // coalesced 32x(x0,x1)
    if (tid < 32) pld[tid] = 0.0f;

    const int lane = tid & 63, wave = tid >> 6;
    const int p = lane & 31, kh = lane >> 5;
    const int hb0 = 2 * wave, hb1 = 2 * wave + 1;             // two hidden blocks per wave
    const int abase  = p * AS + kh * 8;                       // act-frag base (+kk*16)
    const int ebase0 = p * AS + hb0 * 32 + kh * 4;            // el_write bases
    const int ebase1 = p * AS + hb1 * 32 + kh * 4;
    const int wub0   = hb0 * 64 + lane;                       // weight bf16x8-unit bases (+kk*512)
    const int wub1   = hb1 * 64 + lane;
    const int bbase0 = hb0 * 32 + kh * 4;                     // bias seed bases (+8*g)
    const int bbase1 = hb1 * 32 + kh * 4;

    const int p4 = tid >> 3;            // point (0..31)
    const int ic = tid & 7;             // 8 threads per point, 32 hidden each

    const float b40 = b4g[0], b41 = b4g[1];
    __syncthreads();

#pragma unroll 1
    for (int st = 0; st < 10; ++st) {
        const float ti = 0.1f * (float)st;
        // ---------- layer 1 (fused with previous step's L4; registers only) ----------
        // cb = g*32 + ic*4: 16B/lane stride across ic
        const float x0 = px[p4][0];   // broadcast ds_read (same wave wrote it)
        const float x1 = px[p4][1];
#pragma unroll
        for (int g = 0; g < 8; ++g) {
            const int cb = g * 32 + (ic << 2);
            const f4s wa = ld4(&w1r[0][cb]);
            const f4s wb = ld4(&w1r[1][cb]);
            const f4s wc = ld4(&w1r[2][cb]);
            const f4s bs = ld4(&basel[cb]);
            float hf[4], t0f[4], t1f[4];
#pragma unroll
            for (int e = 0; e < 4; ++e) {
                const float pre = x0 * wa.v[e] + x1 * wb.v[e] + ti * wc.v[e] + bs.v[e];
                const float s = sigm(pre);
                const float h = pre * s;
                const float d = fmaf(h, 1.0f - s, s);
                hf[e]  = h;
                t0f[e] = d * wa.v[e];
                t1f[e] = d * wb.v[e];
            }
            uint2 v0, v1, v2;
            v0.x = cvtpk(hf[0],  hf[1]);  v0.y = cvtpk(hf[2],  hf[3]);
            v1.x = cvtpk(t0f[0], t0f[1]); v1.y = cvtpk(t0f[2], t0f[3]);
            v2.x = cvtpk(t1f[0], t1f[1]); v2.y = cvtpk(t1f[2], t1f[3]);
            *(uint2*)(Asl + p4 * AS + cb) = v0;
            *(uint2*)(Asl + T0OFF + p4 * AS + cb) = v1;
            *(uint2*)(Asl + T1OFF + p4 * AS + cb) = v2;
        }
        __syncthreads();

        // ---------- layer 2 ----------
        f32x16 aP0, aT00, aT10, aP1, aT01, aT11;
#pragma unroll
        for (int g = 0; g < 4; ++g) {
            const float4 bv0 = *(const float4*)&b2l[bbase0 + 8 * g];   // broadcast reads
            const float4 bv1 = *(const float4*)&b2l[bbase1 + 8 * g];
            aP0[4 * g + 0] = bv0.x; aP0[4 * g + 1] = bv0.y;
            aP0[4 * g + 2] = bv0.z; aP0[4 * g + 3] = bv0.w;
            aP1[4 * g + 0] = bv1.x; aP1[4 * g + 1] = bv1.y;
            aP1[4 * g + 2] = bv1.z; aP1[4 * g + 3] = bv1.w;
        }
#pragma unroll
        for (int r = 0; r < 16; ++r) { aT00[r] = 0.f; aT10[r] = 0.f; aT01[r] = 0.f; aT11[r] = 0.f; }
        {
            const bf16x8* __restrict__ wp = (const bf16x8*)w2f;
            bf16x8 b0[4], b1[4];
#pragma unroll
            for (int i = 0; i < 4; ++i) { b0[i] = wp[wub0 + i * 512]; b1[i] = wp[wub1 + i * 512]; }
#pragma unroll 1
            for (int kk = 0; kk < 12; kk += 4) {
#pragma unroll
                for (int u = 0; u < 4; ++u) {
                    MFMA6((kk + u) * 16, b0[u], b1[u]);
                    b0[u] = wp[wub0 + (kk + 4 + u) * 512];   // prefetch distance 4
                    b1[u] = wp[wub1 + (kk + 4 + u) * 512];
                }
            }
#pragma unroll
            for (int u = 0; u < 4; ++u) MFMA6((12 + u) * 16, b0[u], b1[u]);
        }
        __syncthreads();                      // all waves done READING Asl before overwrite
        el_write32(Asl, aP0, aT00, aT10, ebase0);
        el_write32(Asl, aP1, aT01, aT11, ebase1);
        __syncthreads();

        // ---------- layer 3 ----------
#pragma unroll
        for (int g = 0; g < 4; ++g) {
            const float4 bv0 = *(const float4*)&b3l[bbase0 + 8 * g];
            const float4 bv1 = *(const float4*)&b3l[bbase1 + 8 * g];
            aP0[4 * g + 0] = bv0.x; aP0[4 * g + 1] = bv0.y;
            aP0[4 * g + 2] = bv0.z; aP0[4 * g + 3] = bv0.w;
            aP1[4 * g + 0] = bv1.x; aP1[4 * g + 1] = bv1.y;
            aP1[4 * g + 2] = bv1.z; aP1[4 * g + 3] = bv1.w;
        }
#pragma unroll
        for (int r = 0; r < 16; ++r) { aT00[r] = 0.f; aT10[r] = 0.f; aT01[r] = 0.f; aT11[r] = 0.f; }
        {
            const bf16x8* __restrict__ wp = (const bf16x8*)w3f;
            bf16x8 b0[4], b1[4];
#pragma unroll
            for (int i = 0; i < 4; ++i) { b0[i] = wp[wub0 + i * 512]; b1[i] = wp[wub1 + i * 512]; }
#pragma unroll 1
            for (int kk = 0; kk < 12; kk += 4) {
#pragma unroll
                for (int u = 0; u < 4; ++u) {
                    MFMA6((kk + u) * 16, b0[u], b1[u]);
                    b0[u] = wp[wub0 + (kk + 4 + u) * 512];
                    b1[u] = wp[wub1 + (kk + 4 + u) * 512];
                }
            }
#pragma unroll
            for (int u = 0; u < 4; ++u) MFMA6((12 + u) * 16, b0[u], b1[u]);
        }
        __syncthreads();
        el_write32(Asl, aP0, aT00, aT10, ebase0);
        el_write32(Asl, aP1, aT01, aT11, ebase1);
        __syncthreads();

        // ---------- layer 4 + point update (same-wave LDS state; no trailing barrier) ----------
        {
            float v0 = 0.f, v1 = 0.f, j00 = 0.f, j11 = 0.f;
#pragma unroll
            for (int g = 0; g < 8; ++g) {
                const int cb = g * 32 + (ic << 2);
                const uint2 hv  = *(const uint2*)(Asl + p4 * AS + cb);
                const uint2 t0v = *(const uint2*)(Asl + T0OFF + p4 * AS + cb);
                const uint2 t1v = *(const uint2*)(Asl + T1OFF + p4 * AS + cb);
                const f4s wa = ld4(&w40[cb]);
                const f4s wb = ld4(&w41[cb]);
                const unsigned hu[4]  = { hv.x & 0xffffu,  hv.x >> 16,  hv.y & 0xffffu,  hv.y >> 16 };
                const unsigned t0u[4] = { t0v.x & 0xffffu, t0v.x >> 16, t0v.y & 0xffffu, t0v.y >> 16 };
                const unsigned t1u[4] = { t1v.x & 0xffffu, t1v.x >> 16, t1v.y & 0xffffu, t1v.y >> 16 };
#pragma unroll
                for (int e = 0; e < 4; ++e) {
                    const float h = bf2f(hu[e]);
                    v0  += h * wa.v[e];
                    v1  += h * wb.v[e];
                    j00 += bf2f(t0u[e]) * wa.v[e];
                    j11 += bf2f(t1u[e]) * wb.v[e];
                }
            }
#pragma unroll
            for (int o = 1; o < 8; o <<= 1) {    // butterfly across the point's 8 lanes
                v0  += __shfl_xor(v0, o);
                v1  += __shfl_xor(v1, o);
                j00 += __shfl_xor(j00, o);
                j11 += __shfl_xor(j11, o);
            }
            if (ic == 0) {                       // same wave as the 8 reader lanes
                px[p4][0] += 0.1f * (v0 + b40);
                px[p4][1] += 0.1f * (v1 + b41);
                pld[p4]   += 0.1f * (j00 + j11);
            }
            // next L1 reads px (same wave) and overwrites the Asl addresses this
            // thread just read: no barrier.
        }
    }

    // ---------- epilogue: FP32 output ----------
    if (ic == 0) {
        out[((b << 12) + n0 + p4) * 2]     = px[p4][0];
        out[((b << 12) + n0 + p4) * 2 + 1] = px[p4][1];
    }
    __syncthreads();
    if (wave == 0) {
        float v = (lane < 32) ? pld[lane] : 0.0f;
#pragma unroll
        for (int o = 32; o > 0; o >>= 1) v += __shfl_xor(v, o);
        if (lane == 0) atomicAdd(ldacc + b, v);
    }
}

// copy 64 float accumulators -> fp32 logdet outputs
__global__ void k_fin(const float* __restrict__ ldacc, float* __restrict__ out) {
    out[524288 + threadIdx.x] = ldacc[threadIdx.x];
}

extern "C" void kernel_launch(void* const* d_in, const int* in_sizes, int n_in,
                              void* d_out, int out_size, void* d_ws, size_t ws_size,
                              hipStream_t stream) {
    const float* x   = (const float*)d_in[0];
    const float* ctx = (const float*)d_in[1];
    const float* w1  = (const float*)d_in[2];
    const float* b1  = (const float*)d_in[3];
    const float* w2  = (const float*)d_in[4];
    const float* b2  = (const float*)d_in[5];
    const float* w3  = (const float*)d_in[6];
    const float* b3  = (const float*)d_in[7];
    const float* w4  = (const float*)d_in[8];
    const float* b4  = (const float*)d_in[9];

    // d_ws layout: [0,128K) w2f bf16 | [128K,256K) w3f bf16 | [256K,320K) base fp32 | [320K,+256) ldacc
    char* ws = (char*)d_ws;
    unsigned short* w2f = (unsigned short*)ws;
    unsigned short* w3f = (unsigned short*)(ws + 131072);
    float* basep = (float*)(ws + 262144);
    float* ldacc = (float*)(ws + 327680);
    float* out = (float*)d_out;

    hipMemsetAsync(ldacc, 0, 64 * sizeof(float), stream);
    k_base<<<dim3(64), dim3(256), 0, stream>>>(ctx, w1, b1, basep);
    k_frag<<<dim3(128), dim3(512), 0, stream>>>(w2, w2f);
    k_frag<<<dim3(128), dim3(512), 0, stream>>>(w3, w3f);
    k_main<<<dim3(8192), dim3(256), 0, stream>>>(x, w1, b2, b3, w4, b4, w2f, w3f, basep, ldacc, out);
    k_fin<<<dim3(1), dim3(64), 0, stream>>>(ldacc, out);
}